// Round 5
// baseline (1920.730 us; speedup 1.0000x reference)
//
#include <hip/hip_runtime.h>
#include <hip/hip_bf16.h>
#include <math.h>

// Problem constants
#define NC 3
#define NK 64
#define KK 3
#define K2 9
#define PAD 1
#define SCALE 4
#define S2 16
#define MID 4
#define B 4
#define H 128
#define W 128
#define HW (H*W)          // 16384
#define CIN 67            // NK + NC
#define OUT_HW (H*SCALE)  // 512

__device__ __forceinline__ float fast_sigmoid(float v) { return 1.f / (1.f + __expf(-v)); }
__device__ __forceinline__ float fast_tanh(float v) { return 2.f / (1.f + __expf(-2.f * v)) - 1.f; }

// load a zero-padded 3x3 patch of one channel plane (HxW) at (y,x)
__device__ __forceinline__ void load_patch(const float* __restrict__ xc, int y, int x, float* p) {
#pragma unroll
    for (int dy = -1; dy <= 1; dy++) {
#pragma unroll
        for (int dx = -1; dx <= 1; dx++) {
            int yy = y + dy, xx = x + dx;
            float v = (yy >= 0 && yy < H && xx >= 0 && xx < W) ? xc[yy * W + xx] : 0.f;
            p[(dy + 1) * 3 + (dx + 1)] = v;
        }
    }
}

// ---------------------------------------------------------------------------
// ConvLSTM with h=0,c=0: only first NC input channels of lstm_w matter;
// f-gate irrelevant (c_prev=0). blockIdx.y selects a 16-channel gate group.
// ---------------------------------------------------------------------------
__global__ __launch_bounds__(256) void k_lstm(const float* __restrict__ X,
                                              const float* __restrict__ lw,
                                              const float* __restrict__ lb,
                                              float* __restrict__ xcatA,
                                              float* __restrict__ hid_out,
                                              float* __restrict__ cell_out) {
    int t = blockIdx.x * blockDim.x + threadIdx.x;
    int b = t >> 14, hw = t & (HW - 1), y = hw >> 7, x = hw & (W - 1);
    int nk0 = blockIdx.y * 16;
    float p[NC][9];
#pragma unroll
    for (int c = 0; c < NC; c++) load_patch(X + (b * NC + c) * HW, y, x, p[c]);
    float* xc = xcatA + (size_t)b * CIN * HW;
    for (int i = 0; i < 16; i++) {
        int nk = nk0 + i;
        float gi = lb[nk], go = lb[2 * NK + nk], gg = lb[3 * NK + nk];
#pragma unroll
        for (int c = 0; c < NC; c++) {
            const float* wi = lw + (size_t)(nk) * (CIN * 9) + c * 9;
            const float* wo = lw + (size_t)(2 * NK + nk) * (CIN * 9) + c * 9;
            const float* wg = lw + (size_t)(3 * NK + nk) * (CIN * 9) + c * 9;
#pragma unroll
            for (int tt = 0; tt < 9; tt++) {
                gi += p[c][tt] * wi[tt];
                go += p[c][tt] * wo[tt];
                gg += p[c][tt] * wg[tt];
            }
        }
        float cv = fast_sigmoid(gi) * fast_tanh(gg);
        float hv = fast_sigmoid(go) * fast_tanh(cv);
        xc[nk * HW + hw] = hv;
        hid_out[(b * NK + nk) * HW + hw] = hv;
        cell_out[(b * NK + nk) * HW + hw] = cv;
    }
}

// copy lr (X) into channels 64..66 of both xcat buffers
__global__ __launch_bounds__(256) void k_copy_lr(const float* __restrict__ X,
                                                 float* __restrict__ xcatA,
                                                 float* __restrict__ xcatB) {
    int t = blockIdx.x * blockDim.x + threadIdx.x;
    int b = t >> 14, hw = t & (HW - 1);
#pragma unroll
    for (int c = 0; c < NC; c++) {
        float v = X[(b * NC + c) * HW + hw];
        xcatA[(size_t)b * CIN * HW + (NK + c) * HW + hw] = v;
        xcatB[(size_t)b * CIN * HW + (NK + c) * HW + hw] = v;
    }
}

// transpose deform main weight w[o][c][k] (o<64, c<67, k<9) -> wT[k][c][o]
__global__ void k_transw(const float* __restrict__ w, float* __restrict__ wT) {
    int i = blockIdx.x * blockDim.x + threadIdx.x;
    if (i < NK * CIN * K2) {
        int o = i / (CIN * K2), r = i % (CIN * K2);
        int c = r / K2, k = r % K2;
        wT[((size_t)k * CIN + c) * NK + o] = w[i];
    }
}

// ---------------------------------------------------------------------------
// Offset + mask convs, c-split. Block = 256 threads = 64 pixels; the 4 waves
// partition the 67 input channels (16/17/17/17); each wave accumulates all 27
// outputs in VGPRs (static indices only). LDS reduction, then offsets stored
// raw and mask as 2*sigmoid. XCD-contiguous strip swizzle.
// ---------------------------------------------------------------------------
__global__ __launch_bounds__(256, 4) void k_offmask(const float* __restrict__ xcat,
                                                    const float* __restrict__ ow,
                                                    const float* __restrict__ ob,
                                                    const float* __restrict__ mw,
                                                    const float* __restrict__ mb,
                                                    float* __restrict__ offb,
                                                    float* __restrict__ maskb) {
    __shared__ float red[4 * 27 * 64];  // 27648 B
    int lane = threadIdx.x & 63;
    int wid = threadIdx.x >> 6;
    int blk = blockIdx.x;
    int sg = (blk & 7) * 128 + (blk >> 3);  // XCD-contiguous strip id
    int b = sg >> 8;
    int hwbase = (sg & 255) * 64;
    int hw = hwbase + lane, y = hw >> 7, x = hw & (W - 1);
    int c0 = (CIN * wid) >> 2, c1 = (CIN * (wid + 1)) >> 2;

    float acc[27];
#pragma unroll
    for (int i = 0; i < 27; i++) acc[i] = 0.f;
    const float* xb = xcat + (size_t)b * CIN * HW;
    for (int c = c0; c < c1; c++) {
        float p[9];
        load_patch(xb + c * HW, y, x, p);
#pragma unroll
        for (int oc = 0; oc < 18; oc++) {
            const float* w = ow + (size_t)oc * (CIN * 9) + c * 9;
#pragma unroll
            for (int tt = 0; tt < 9; tt++) acc[oc] += p[tt] * w[tt];
        }
#pragma unroll
        for (int oc = 0; oc < 9; oc++) {
            const float* w = mw + (size_t)oc * (CIN * 9) + c * 9;
#pragma unroll
            for (int tt = 0; tt < 9; tt++) acc[18 + oc] += p[tt] * w[tt];
        }
    }
#pragma unroll
    for (int j = 0; j < 27; j++) red[(wid * 27 + j) * 64 + lane] = acc[j];
    __syncthreads();
    for (int idx = threadIdx.x; idx < 27 * 64; idx += 256) {
        int j = idx >> 6, px = idx & 63;
        float s = red[j * 64 + px] + red[(27 + j) * 64 + px]
                + red[(54 + j) * 64 + px] + red[(81 + j) * 64 + px];
        if (j < 18) {
            offb[(b * 18 + j) * HW + hwbase + px] = s + ob[j];
        } else {
            int mj = j - 18;
            maskb[(b * 9 + mj) * HW + hwbase + px] = 2.f * fast_sigmoid(s + mb[mj]);
        }
    }
}

// ---------------------------------------------------------------------------
// Deformable gather + einsum, hybrid o/c split. Block = 256 threads = 64 px;
// wave w handles output-half (w&1, 32 accs) x channel-half (w>>1, ~34 ch).
// 32 accs + 8 staged float4 weights + bilinear state ~= 90 VGPR < 128 cap
// -> no scratch spill (rounds 1-4 all spilled with 64 accs/wave).
// Gathers duplicate 2x across o-halves (L1-served). Single-barrier LDS
// reduction pairs (w, w+2). XCD-contiguous strip swizzle.
// ---------------------------------------------------------------------------
__global__ __launch_bounds__(256, 4) void k_deform(const float* __restrict__ xcat,
                                                   const float* __restrict__ offb,
                                                   const float* __restrict__ maskb,
                                                   const float* __restrict__ wT,
                                                   const float* __restrict__ bias,
                                                   float* __restrict__ xout) {
    __shared__ float red[4 * 32 * 64];  // 32 KB
    int lane = threadIdx.x & 63;
    int wid = threadIdx.x >> 6;
    int ohalf = (wid & 1) * 32;          // output channels [ohalf, ohalf+32)
    int chalf = wid >> 1;                // channel half
    int c0 = chalf ? 34 : 0;
    int c1 = chalf ? CIN : 34;

    int blk = blockIdx.x;
    int sg = (blk & 7) * 128 + (blk >> 3);  // XCD-contiguous strip id
    int b = sg >> 8;
    int hwbase = (sg & 255) * 64;
    int hw = hwbase + lane;
    int y = hw >> 7, x = hw & (W - 1);

    float acc[32];
#pragma unroll
    for (int o = 0; o < 32; o++) acc[o] = 0.f;

    const float* xb = xcat + (size_t)b * CIN * HW;
#pragma unroll
    for (int k = 0; k < K2; k++) {
        int ky = k / 3, kx = k % 3;
        float offy = offb[(b * 18 + 2 * k) * HW + hw];
        float offx = offb[(b * 18 + 2 * k + 1) * HW + hw];
        float m = maskb[(b * 9 + k) * HW + hw];
        float py = (float)(y + ky - 1) + offy;
        float px_ = (float)(x + kx - 1) + offx;
        float fy = floorf(py), fx = floorf(px_);
        float wy = py - fy, wx = px_ - fx;
        int y0 = (int)fy, x0 = (int)fx;
        int y1 = y0 + 1, x1 = x0 + 1;
        float vy0 = (y0 >= 0 && y0 <= H - 1) ? 1.f : 0.f;
        float vy1 = (y1 >= 0 && y1 <= H - 1) ? 1.f : 0.f;
        float vx0 = (x0 >= 0 && x0 <= W - 1) ? 1.f : 0.f;
        float vx1 = (x1 >= 0 && x1 <= W - 1) ? 1.f : 0.f;
        int yc0 = min(max(y0, 0), H - 1), yc1 = min(max(y1, 0), H - 1);
        int xc0 = min(max(x0, 0), W - 1), xc1 = min(max(x1, 0), W - 1);
        float a00 = (1.f - wy) * (1.f - wx) * m * vy0 * vx0;
        float a01 = (1.f - wy) * wx * m * vy0 * vx1;
        float a10 = wy * (1.f - wx) * m * vy1 * vx0;
        float a11 = wy * wx * m * vy1 * vx1;
        int j00 = yc0 * W + xc0, j01 = yc0 * W + xc1;
        int j10 = yc1 * W + xc0, j11 = yc1 * W + xc1;

        const float* wk = wT + (size_t)k * CIN * NK + ohalf;
#pragma unroll 1
        for (int c = c0; c < c1; c++) {
            const float* xc = xb + c * HW;
            float v = a00 * xc[j00] + a01 * xc[j01] + a10 * xc[j10] + a11 * xc[j11];
            const float4* wv4 = (const float4*)(wk + (size_t)c * NK);
#pragma unroll
            for (int q = 0; q < 8; q++) {
                float4 wq = wv4[q];
                acc[4 * q + 0] += v * wq.x;
                acc[4 * q + 1] += v * wq.y;
                acc[4 * q + 2] += v * wq.z;
                acc[4 * q + 3] += v * wq.w;
            }
        }
    }

    // single-barrier LDS reduction: pair (wid, wid^2) share the same o-half
#pragma unroll
    for (int j = 0; j < 32; j++) red[(wid * 32 + j) * 64 + lane] = acc[j];
    __syncthreads();

    float* xo = xout + (size_t)b * CIN * HW + hwbase;
#pragma unroll
    for (int j = 0; j < 16; j++) {
        int oc = wid * 16 + j;           // 0..63
        int base = (oc >> 5);            // 0 -> waves {0,2}, 1 -> waves {1,3}
        int jj = oc & 31;
        float s = red[((base * 32) + jj) * 64 + lane]
                + red[(((base + 2) * 32) + jj) * 64 + lane];
        xo[oc * HW + lane] = s + bias[oc];
    }
}

// final 3-channel conv over 67-channel concat; blockIdx.y = output channel
__global__ __launch_bounds__(256) void k_conv3(const float* __restrict__ xcat,
                                               const float* __restrict__ cw,
                                               const float* __restrict__ cb,
                                               float* __restrict__ y3) {
    int t = blockIdx.x * blockDim.x + threadIdx.x;
    int b = t >> 14, hw = t & (HW - 1), y = hw >> 7, x = hw & (W - 1);
    int oc = blockIdx.y;
    float acc = cb[oc];
    const float* xb = xcat + (size_t)b * CIN * HW;
    const float* wb = cw + (size_t)oc * (CIN * 9);
    for (int c = 0; c < CIN; c++) {
        float p[9];
        load_patch(xb + c * HW, y, x, p);
        const float* w = wb + c * 9;
#pragma unroll
        for (int tt = 0; tt < 9; tt++) acc += p[tt] * w[tt];
    }
    y3[(b * NC + oc) * HW + hw] = acc;
}

// global average pool: one block per (b,c)
__global__ __launch_bounds__(256) void k_pool(const float* __restrict__ y3,
                                              float* __restrict__ pooled) {
    int bc = blockIdx.x;  // 0..11
    const float* p = y3 + (size_t)bc * HW;
    float s = 0.f;
    for (int i = threadIdx.x; i < HW; i += 256) s += p[i];
    __shared__ float red[256];
    red[threadIdx.x] = s;
    __syncthreads();
    for (int off = 128; off > 0; off >>= 1) {
        if (threadIdx.x < off) red[threadIdx.x] += red[threadIdx.x + off];
        __syncthreads();
    }
    if (threadIdx.x == 0) pooled[bc] = red[0] / (float)HW;
}

// tiny per-branch channel MLP -> ch[b,s,c,k]
__global__ void k_ch(const float* __restrict__ pooled, const float* __restrict__ w1,
                     const float* __restrict__ b1, const float* __restrict__ w2,
                     const float* __restrict__ b2, float* __restrict__ chbuf) {
    int t = threadIdx.x;
    if (t >= B * S2) return;
    int b = t >> 4, s = t & 15;
    float h1[MID];
#pragma unroll
    for (int m = 0; m < MID; m++) {
        float a = b1[s * MID + m];
#pragma unroll
        for (int c = 0; c < NC; c++) a += pooled[b * NC + c] * w1[(s * MID + m) * NC + c];
        h1[m] = fmaxf(a, 0.f);
    }
    for (int kk = 0; kk < NC * K2; kk++) {
        float a = b2[s * (NC * K2) + kk];
#pragma unroll
        for (int m = 0; m < MID; m++) a += h1[m] * w2[(s * (NC * K2) + kk) * MID + m];
        chbuf[(b * S2 + s) * (NC * K2) + kk] = a;
    }
}

// ---------------------------------------------------------------------------
// Fused DDF upsample: spatial-filter conv + dynamic combine + pixel_shuffle
// + clip. blockIdx.y selects 4 of the 16 branches; that quarter of sp_w/sp_b
// and ch staged in LDS (block is single-batch).
// ---------------------------------------------------------------------------
__global__ __launch_bounds__(256) void k_ddf(const float* __restrict__ y3,
                                             const float* __restrict__ spw,
                                             const float* __restrict__ spb,
                                             const float* __restrict__ chbuf,
                                             float* __restrict__ out) {
    __shared__ float s_spw[4 * K2 * NC * 9];  // 972
    __shared__ float s_spb[4 * K2];           // 36
    __shared__ float s_ch[4 * NC * K2];       // 108
    int t = blockIdx.x * blockDim.x + threadIdx.x;
    int b = t >> 14, hw = t & (HW - 1), y = hw >> 7, x = hw & (W - 1);
    int s0 = blockIdx.y * 4;
    for (int i = threadIdx.x; i < 4 * K2 * NC * 9; i += 256) s_spw[i] = spw[s0 * K2 * NC * 9 + i];
    if (threadIdx.x < 4 * K2) s_spb[threadIdx.x] = spb[s0 * K2 + threadIdx.x];
    if (threadIdx.x < 4 * NC * K2) s_ch[threadIdx.x] = chbuf[b * (S2 * NC * K2) + s0 * NC * K2 + threadIdx.x];
    __syncthreads();
    float p[NC][9];
#pragma unroll
    for (int c = 0; c < NC; c++) load_patch(y3 + (b * NC + c) * HW, y, x, p[c]);
#pragma unroll
    for (int si = 0; si < 4; si++) {
        int s = s0 + si;
        float spv[K2];
#pragma unroll
        for (int k = 0; k < K2; k++) {
            float a = s_spb[si * K2 + k];
            const float* w = s_spw + (si * K2 + k) * (NC * 9);
#pragma unroll
            for (int c = 0; c < NC; c++)
#pragma unroll
                for (int tt = 0; tt < 9; tt++) a += p[c][tt] * w[c * 9 + tt];
            spv[k] = a;
        }
        int sy = s >> 2, sx = s & 3;
#pragma unroll
        for (int c = 0; c < NC; c++) {
            float a = 0.f;
            const float* chp = s_ch + (si * NC + c) * K2;
#pragma unroll
            for (int k = 0; k < K2; k++) a += p[c][k] * (chp[k] + spv[k]);
            a = fminf(fmaxf(a, 0.f), 255.f);
            out[((size_t)(b * NC + c) * OUT_HW + (y * SCALE + sy)) * OUT_HW + (x * SCALE + sx)] = a;
        }
    }
}

extern "C" void kernel_launch(void* const* d_in, const int* in_sizes, int n_in,
                              void* d_out, int out_size, void* d_ws, size_t ws_size,
                              hipStream_t stream) {
    const float* X = (const float*)d_in[0];
    const float* lstm_w = (const float*)d_in[1];
    const float* lstm_b = (const float*)d_in[2];
    const float* ow[3] = {(const float*)d_in[3], (const float*)d_in[9], (const float*)d_in[15]};
    const float* ob[3] = {(const float*)d_in[4], (const float*)d_in[10], (const float*)d_in[16]};
    const float* mw[3] = {(const float*)d_in[5], (const float*)d_in[11], (const float*)d_in[17]};
    const float* mb[3] = {(const float*)d_in[6], (const float*)d_in[12], (const float*)d_in[18]};
    const float* dw[3] = {(const float*)d_in[7], (const float*)d_in[13], (const float*)d_in[19]};
    const float* db[3] = {(const float*)d_in[8], (const float*)d_in[14], (const float*)d_in[20]};
    const float* conv_w = (const float*)d_in[21];
    const float* conv_b = (const float*)d_in[22];
    const float* sp_w = (const float*)d_in[23];
    const float* sp_b = (const float*)d_in[24];
    const float* ch_w1 = (const float*)d_in[25];
    const float* ch_b1 = (const float*)d_in[26];
    const float* ch_w2 = (const float*)d_in[27];
    const float* ch_b2 = (const float*)d_in[28];

    float* out = (float*)d_out;
    const size_t OUT_IMG = (size_t)B * NC * OUT_HW * OUT_HW;  // 3145728
    const size_t HIDSZ = (size_t)B * NK * HW;                 // 4194304
    float* hid_out = out + OUT_IMG;
    float* cell_out = out + OUT_IMG + HIDSZ;

    float* ws = (float*)d_ws;
    const size_t XCAT = (size_t)B * CIN * HW;  // 4390912
    float* xcatA = ws;            ws += XCAT;
    float* xcatB = ws;            ws += XCAT;
    float* offb = ws;             ws += (size_t)B * 18 * HW;
    float* maskb = ws;            ws += (size_t)B * 9 * HW;
    float* wT[3];
    for (int i = 0; i < 3; i++) { wT[i] = ws; ws += NK * CIN * K2; }
    float* y3 = ws;               ws += (size_t)B * NC * HW;
    float* pooled = ws;           ws += 16;
    float* chbuf = ws;            ws += (size_t)B * S2 * NC * K2;

    dim3 blk(256);
    dim3 g1(B * HW / 256);        // 256 blocks
    dim3 g4(B * HW / 256, 4);
    dim3 g3(B * HW / 256, 3);
    dim3 gd(B * HW / 64);         // 1024 blocks for split deform/offmask

    k_lstm<<<g4, blk, 0, stream>>>(X, lstm_w, lstm_b, xcatA, hid_out, cell_out);
    k_copy_lr<<<g1, blk, 0, stream>>>(X, xcatA, xcatB);
    int ntw = NK * CIN * K2;
    for (int i = 0; i < 3; i++)
        k_transw<<<(ntw + 255) / 256, 256, 0, stream>>>(dw[i], wT[i]);

    // layer 1: xcatA -> xcatB
    k_offmask<<<gd, blk, 0, stream>>>(xcatA, ow[0], ob[0], mw[0], mb[0], offb, maskb);
    k_deform<<<gd, blk, 0, stream>>>(xcatA, offb, maskb, wT[0], db[0], xcatB);
    // layer 2: xcatB -> xcatA
    k_offmask<<<gd, blk, 0, stream>>>(xcatB, ow[1], ob[1], mw[1], mb[1], offb, maskb);
    k_deform<<<gd, blk, 0, stream>>>(xcatB, offb, maskb, wT[1], db[1], xcatA);
    // layer 3: xcatA -> xcatB
    k_offmask<<<gd, blk, 0, stream>>>(xcatA, ow[2], ob[2], mw[2], mb[2], offb, maskb);
    k_deform<<<gd, blk, 0, stream>>>(xcatA, offb, maskb, wT[2], db[2], xcatB);

    k_conv3<<<g3, blk, 0, stream>>>(xcatB, conv_w, conv_b, y3);
    k_pool<<<dim3(B * NC), blk, 0, stream>>>(y3, pooled);
    k_ch<<<dim3(1), dim3(64), 0, stream>>>(pooled, ch_w1, ch_b1, ch_w2, ch_b2, chbuf);
    k_ddf<<<g4, blk, 0, stream>>>(y3, sp_w, sp_b, chbuf, out);
}

// Round 6
// 899.265 us; speedup vs baseline: 2.1359x; 2.1359x over previous
//
#include <hip/hip_runtime.h>
#include <hip/hip_bf16.h>
#include <math.h>

// Problem constants
#define NC 3
#define NK 64
#define KK 3
#define K2 9
#define PAD 1
#define SCALE 4
#define S2 16
#define MID 4
#define B 4
#define H 128
#define W 128
#define HW (H*W)          // 16384
#define CIN 67            // NK + NC
#define OUT_HW (H*SCALE)  // 512

__device__ __forceinline__ float fast_sigmoid(float v) { return 1.f / (1.f + __expf(-v)); }
__device__ __forceinline__ float fast_tanh(float v) { return 2.f / (1.f + __expf(-2.f * v)) - 1.f; }

// load a zero-padded 3x3 patch of one channel plane (HxW) at (y,x)
__device__ __forceinline__ void load_patch(const float* __restrict__ xc, int y, int x, float* p) {
#pragma unroll
    for (int dy = -1; dy <= 1; dy++) {
#pragma unroll
        for (int dx = -1; dx <= 1; dx++) {
            int yy = y + dy, xx = x + dx;
            float v = (yy >= 0 && yy < H && xx >= 0 && xx < W) ? xc[yy * W + xx] : 0.f;
            p[(dy + 1) * 3 + (dx + 1)] = v;
        }
    }
}

// ---------------------------------------------------------------------------
// ConvLSTM with h=0,c=0: only first NC input channels of lstm_w matter;
// f-gate irrelevant (c_prev=0). blockIdx.y selects a 16-channel gate group.
// ---------------------------------------------------------------------------
__global__ __launch_bounds__(256) void k_lstm(const float* __restrict__ X,
                                              const float* __restrict__ lw,
                                              const float* __restrict__ lb,
                                              float* __restrict__ xcatA,
                                              float* __restrict__ hid_out,
                                              float* __restrict__ cell_out) {
    int t = blockIdx.x * blockDim.x + threadIdx.x;
    int b = t >> 14, hw = t & (HW - 1), y = hw >> 7, x = hw & (W - 1);
    int nk0 = blockIdx.y * 16;
    float p[NC][9];
#pragma unroll
    for (int c = 0; c < NC; c++) load_patch(X + (b * NC + c) * HW, y, x, p[c]);
    float* xc = xcatA + (size_t)b * CIN * HW;
    for (int i = 0; i < 16; i++) {
        int nk = nk0 + i;
        float gi = lb[nk], go = lb[2 * NK + nk], gg = lb[3 * NK + nk];
#pragma unroll
        for (int c = 0; c < NC; c++) {
            const float* wi = lw + (size_t)(nk) * (CIN * 9) + c * 9;
            const float* wo = lw + (size_t)(2 * NK + nk) * (CIN * 9) + c * 9;
            const float* wg = lw + (size_t)(3 * NK + nk) * (CIN * 9) + c * 9;
#pragma unroll
            for (int tt = 0; tt < 9; tt++) {
                gi += p[c][tt] * wi[tt];
                go += p[c][tt] * wo[tt];
                gg += p[c][tt] * wg[tt];
            }
        }
        float cv = fast_sigmoid(gi) * fast_tanh(gg);
        float hv = fast_sigmoid(go) * fast_tanh(cv);
        xc[nk * HW + hw] = hv;
        hid_out[(b * NK + nk) * HW + hw] = hv;
        cell_out[(b * NK + nk) * HW + hw] = cv;
    }
}

// copy lr (X) into channels 64..66 of both xcat buffers
__global__ __launch_bounds__(256) void k_copy_lr(const float* __restrict__ X,
                                                 float* __restrict__ xcatA,
                                                 float* __restrict__ xcatB) {
    int t = blockIdx.x * blockDim.x + threadIdx.x;
    int b = t >> 14, hw = t & (HW - 1);
#pragma unroll
    for (int c = 0; c < NC; c++) {
        float v = X[(b * NC + c) * HW + hw];
        xcatA[(size_t)b * CIN * HW + (NK + c) * HW + hw] = v;
        xcatB[(size_t)b * CIN * HW + (NK + c) * HW + hw] = v;
    }
}

// transpose deform main weight w[o][c][k] (o<64, c<67, k<9) -> wT[k][c][o]
__global__ void k_transw(const float* __restrict__ w, float* __restrict__ wT) {
    int i = blockIdx.x * blockDim.x + threadIdx.x;
    if (i < NK * CIN * K2) {
        int o = i / (CIN * K2), r = i % (CIN * K2);
        int c = r / K2, k = r % K2;
        wT[((size_t)k * CIN + c) * NK + o] = w[i];
    }
}

// ---------------------------------------------------------------------------
// Offset + mask convs, c-split. Block = 256 threads = 64 pixels; the 4 waves
// partition the 67 input channels (16/17/17/17); each wave accumulates all 27
// outputs in VGPRs (static indices only). LDS reduction, then offsets stored
// raw and mask as 2*sigmoid. XCD-contiguous strip swizzle.
// ---------------------------------------------------------------------------
__global__ __launch_bounds__(256, 4) void k_offmask(const float* __restrict__ xcat,
                                                    const float* __restrict__ ow,
                                                    const float* __restrict__ ob,
                                                    const float* __restrict__ mw,
                                                    const float* __restrict__ mb,
                                                    float* __restrict__ offb,
                                                    float* __restrict__ maskb) {
    __shared__ float red[4 * 27 * 64];  // 27648 B
    int lane = threadIdx.x & 63;
    int wid = __builtin_amdgcn_readfirstlane((int)(threadIdx.x >> 6));
    int blk = blockIdx.x;
    int sg = (blk & 7) * 128 + (blk >> 3);  // XCD-contiguous strip id
    int b = sg >> 8;
    int hwbase = (sg & 255) * 64;
    int hw = hwbase + lane, y = hw >> 7, x = hw & (W - 1);
    int c0 = (CIN * wid) >> 2, c1 = (CIN * (wid + 1)) >> 2;

    float acc[27];
#pragma unroll
    for (int i = 0; i < 27; i++) acc[i] = 0.f;
    const float* xb = xcat + (size_t)b * CIN * HW;
    for (int c = c0; c < c1; c++) {
        float p[9];
        load_patch(xb + c * HW, y, x, p);
#pragma unroll
        for (int oc = 0; oc < 18; oc++) {
            const float* w = ow + (size_t)oc * (CIN * 9) + c * 9;
#pragma unroll
            for (int tt = 0; tt < 9; tt++) acc[oc] += p[tt] * w[tt];
        }
#pragma unroll
        for (int oc = 0; oc < 9; oc++) {
            const float* w = mw + (size_t)oc * (CIN * 9) + c * 9;
#pragma unroll
            for (int tt = 0; tt < 9; tt++) acc[18 + oc] += p[tt] * w[tt];
        }
    }
#pragma unroll
    for (int j = 0; j < 27; j++) red[(wid * 27 + j) * 64 + lane] = acc[j];
    __syncthreads();
    for (int idx = threadIdx.x; idx < 27 * 64; idx += 256) {
        int j = idx >> 6, px = idx & 63;
        float s = red[j * 64 + px] + red[(27 + j) * 64 + px]
                + red[(54 + j) * 64 + px] + red[(81 + j) * 64 + px];
        if (j < 18) {
            offb[(b * 18 + j) * HW + hwbase + px] = s + ob[j];
        } else {
            int mj = j - 18;
            maskb[(b * 9 + mj) * HW + hwbase + px] = 2.f * fast_sigmoid(s + mb[mj]);
        }
    }
}

// ---------------------------------------------------------------------------
// One deform tap: bilinear setup (all-scalar state, K compile-time) + c-loop
// of 4 gathers + 32 FMAs against wave-uniform wT slice (o-half ohalf).
// ---------------------------------------------------------------------------
template <int K>
__device__ __forceinline__ void deform_tap(const float* __restrict__ xb,
                                           const float* __restrict__ offb,
                                           const float* __restrict__ maskb,
                                           const float* __restrict__ wT,
                                           int b, int hw, int y, int x, int ohalf,
                                           float (&acc)[32]) {
    constexpr int ky = K / 3, kx = K % 3;
    float offy = offb[(b * 18 + 2 * K) * HW + hw];
    float offx = offb[(b * 18 + 2 * K + 1) * HW + hw];
    float m = maskb[(b * 9 + K) * HW + hw];
    float py = (float)(y + ky - 1) + offy;
    float px_ = (float)(x + kx - 1) + offx;
    float fy = floorf(py), fx = floorf(px_);
    float wy = py - fy, wx = px_ - fx;
    int y0 = (int)fy, x0 = (int)fx;
    int y1 = y0 + 1, x1 = x0 + 1;
    float vy0 = (y0 >= 0 && y0 <= H - 1) ? 1.f : 0.f;
    float vy1 = (y1 >= 0 && y1 <= H - 1) ? 1.f : 0.f;
    float vx0 = (x0 >= 0 && x0 <= W - 1) ? 1.f : 0.f;
    float vx1 = (x1 >= 0 && x1 <= W - 1) ? 1.f : 0.f;
    int yc0 = min(max(y0, 0), H - 1), yc1 = min(max(y1, 0), H - 1);
    int xc0 = min(max(x0, 0), W - 1), xc1 = min(max(x1, 0), W - 1);
    float a00 = (1.f - wy) * (1.f - wx) * m * vy0 * vx0;
    float a01 = (1.f - wy) * wx * m * vy0 * vx1;
    float a10 = wy * (1.f - wx) * m * vy1 * vx0;
    float a11 = wy * wx * m * vy1 * vx1;
    int j00 = yc0 * W + xc0, j01 = yc0 * W + xc1;
    int j10 = yc1 * W + xc0, j11 = yc1 * W + xc1;

    const float* wk = wT + (size_t)K * CIN * NK + ohalf;  // wave-uniform
#pragma unroll 2
    for (int c = 0; c < CIN; c++) {
        const float* xc = xb + c * HW;
        float v = a00 * xc[j00] + a01 * xc[j01] + a10 * xc[j10] + a11 * xc[j11];
        const float4* wv4 = (const float4*)(wk + (size_t)c * NK);
#pragma unroll
        for (int q = 0; q < 8; q++) {
            float4 wq = wv4[q];
            acc[4 * q + 0] += v * wq.x;
            acc[4 * q + 1] += v * wq.y;
            acc[4 * q + 2] += v * wq.z;
            acc[4 * q + 3] += v * wq.w;
        }
    }
}

// ---------------------------------------------------------------------------
// Deformable gather + einsum. Block = 512 threads = 8 waves = 64 pixels.
// Wave w: tap-group (w>>1 in {0-2},{3-4},{5-6},{7-8}) x o-half ((w&1)*32).
// Tap groups dispatched via wave-uniform switch with compile-time taps ->
// no runtime-indexed arrays -> no scratch spill. readfirstlane(wid) makes
// weight addresses provably uniform (scalar-load path). 32 accs/wave.
// Two-chunk LDS reduction (32 KB). XCD-contiguous strip swizzle.
// ---------------------------------------------------------------------------
__global__ __launch_bounds__(512, 4) void k_deform(const float* __restrict__ xcat,
                                                   const float* __restrict__ offb,
                                                   const float* __restrict__ maskb,
                                                   const float* __restrict__ wT,
                                                   const float* __restrict__ bias,
                                                   float* __restrict__ xout) {
    __shared__ float red[8 * 16 * 64];  // 32 KB
    int tid = threadIdx.x;
    int lane = tid & 63;
    int wid = __builtin_amdgcn_readfirstlane(tid >> 6);  // 0..7, uniform
    int ohalf = (wid & 1) * 32;
    int tg = wid >> 1;

    int blk = blockIdx.x;
    int sg = (blk & 7) * 128 + (blk >> 3);  // XCD-contiguous strip id
    int b = sg >> 8;
    int hwbase = (sg & 255) * 64;
    int hw = hwbase + lane;
    int y = hw >> 7, x = hw & (W - 1);

    float acc[32];
#pragma unroll
    for (int o = 0; o < 32; o++) acc[o] = 0.f;

    const float* xb = xcat + (size_t)b * CIN * HW;
    switch (tg) {
        case 0:
            deform_tap<0>(xb, offb, maskb, wT, b, hw, y, x, ohalf, acc);
            deform_tap<1>(xb, offb, maskb, wT, b, hw, y, x, ohalf, acc);
            deform_tap<2>(xb, offb, maskb, wT, b, hw, y, x, ohalf, acc);
            break;
        case 1:
            deform_tap<3>(xb, offb, maskb, wT, b, hw, y, x, ohalf, acc);
            deform_tap<4>(xb, offb, maskb, wT, b, hw, y, x, ohalf, acc);
            break;
        case 2:
            deform_tap<5>(xb, offb, maskb, wT, b, hw, y, x, ohalf, acc);
            deform_tap<6>(xb, offb, maskb, wT, b, hw, y, x, ohalf, acc);
            break;
        default:
            deform_tap<7>(xb, offb, maskb, wT, b, hw, y, x, ohalf, acc);
            deform_tap<8>(xb, offb, maskb, wT, b, hw, y, x, ohalf, acc);
            break;
    }

    // two-chunk LDS reduction across the 4 tap-group waves of each o-half
    float* xo = xout + (size_t)b * CIN * HW + hwbase;
    int px = tid & 63;
    int grp = tid >> 6;            // 0..7
    int h = grp >> 2;              // o-half this thread reduces
    int sub = grp & 3;             // 4-oc sub-chunk
#pragma unroll
    for (int ch = 0; ch < 2; ch++) {
#pragma unroll
        for (int j = 0; j < 16; j++) red[(wid * 16 + j) * 64 + lane] = acc[ch * 16 + j];
        __syncthreads();
#pragma unroll
        for (int j2 = 0; j2 < 4; j2++) {
            int jl = sub * 4 + j2;                 // 0..15
            int oc = h * 32 + ch * 16 + jl;        // 0..63
            float s = red[((0 * 2 + h) * 16 + jl) * 64 + px]
                    + red[((1 * 2 + h) * 16 + jl) * 64 + px]
                    + red[((2 * 2 + h) * 16 + jl) * 64 + px]
                    + red[((3 * 2 + h) * 16 + jl) * 64 + px];
            xo[oc * HW + px] = s + bias[oc];
        }
        __syncthreads();
    }
}

// final 3-channel conv over 67-channel concat; blockIdx.y = output channel
__global__ __launch_bounds__(256) void k_conv3(const float* __restrict__ xcat,
                                               const float* __restrict__ cw,
                                               const float* __restrict__ cb,
                                               float* __restrict__ y3) {
    int t = blockIdx.x * blockDim.x + threadIdx.x;
    int b = t >> 14, hw = t & (HW - 1), y = hw >> 7, x = hw & (W - 1);
    int oc = blockIdx.y;
    float acc = cb[oc];
    const float* xb = xcat + (size_t)b * CIN * HW;
    const float* wb = cw + (size_t)oc * (CIN * 9);
    for (int c = 0; c < CIN; c++) {
        float p[9];
        load_patch(xb + c * HW, y, x, p);
        const float* w = wb + c * 9;
#pragma unroll
        for (int tt = 0; tt < 9; tt++) acc += p[tt] * w[tt];
    }
    y3[(b * NC + oc) * HW + hw] = acc;
}

// global average pool: one block per (b,c)
__global__ __launch_bounds__(256) void k_pool(const float* __restrict__ y3,
                                              float* __restrict__ pooled) {
    int bc = blockIdx.x;  // 0..11
    const float* p = y3 + (size_t)bc * HW;
    float s = 0.f;
    for (int i = threadIdx.x; i < HW; i += 256) s += p[i];
    __shared__ float red[256];
    red[threadIdx.x] = s;
    __syncthreads();
    for (int off = 128; off > 0; off >>= 1) {
        if (threadIdx.x < off) red[threadIdx.x] += red[threadIdx.x + off];
        __syncthreads();
    }
    if (threadIdx.x == 0) pooled[bc] = red[0] / (float)HW;
}

// tiny per-branch channel MLP -> ch[b,s,c,k]
__global__ void k_ch(const float* __restrict__ pooled, const float* __restrict__ w1,
                     const float* __restrict__ b1, const float* __restrict__ w2,
                     const float* __restrict__ b2, float* __restrict__ chbuf) {
    int t = threadIdx.x;
    if (t >= B * S2) return;
    int b = t >> 4, s = t & 15;
    float h1[MID];
#pragma unroll
    for (int m = 0; m < MID; m++) {
        float a = b1[s * MID + m];
#pragma unroll
        for (int c = 0; c < NC; c++) a += pooled[b * NC + c] * w1[(s * MID + m) * NC + c];
        h1[m] = fmaxf(a, 0.f);
    }
    for (int kk = 0; kk < NC * K2; kk++) {
        float a = b2[s * (NC * K2) + kk];
#pragma unroll
        for (int m = 0; m < MID; m++) a += h1[m] * w2[(s * (NC * K2) + kk) * MID + m];
        chbuf[(b * S2 + s) * (NC * K2) + kk] = a;
    }
}

// ---------------------------------------------------------------------------
// Fused DDF upsample: spatial-filter conv + dynamic combine + pixel_shuffle
// + clip. blockIdx.y selects 4 of the 16 branches; that quarter of sp_w/sp_b
// and ch staged in LDS (block is single-batch).
// ---------------------------------------------------------------------------
__global__ __launch_bounds__(256) void k_ddf(const float* __restrict__ y3,
                                             const float* __restrict__ spw,
                                             const float* __restrict__ spb,
                                             const float* __restrict__ chbuf,
                                             float* __restrict__ out) {
    __shared__ float s_spw[4 * K2 * NC * 9];  // 972
    __shared__ float s_spb[4 * K2];           // 36
    __shared__ float s_ch[4 * NC * K2];       // 108
    int t = blockIdx.x * blockDim.x + threadIdx.x;
    int b = t >> 14, hw = t & (HW - 1), y = hw >> 7, x = hw & (W - 1);
    int s0 = blockIdx.y * 4;
    for (int i = threadIdx.x; i < 4 * K2 * NC * 9; i += 256) s_spw[i] = spw[s0 * K2 * NC * 9 + i];
    if (threadIdx.x < 4 * K2) s_spb[threadIdx.x] = spb[s0 * K2 + threadIdx.x];
    if (threadIdx.x < 4 * NC * K2) s_ch[threadIdx.x] = chbuf[b * (S2 * NC * K2) + s0 * NC * K2 + threadIdx.x];
    __syncthreads();
    float p[NC][9];
#pragma unroll
    for (int c = 0; c < NC; c++) load_patch(y3 + (b * NC + c) * HW, y, x, p[c]);
#pragma unroll
    for (int si = 0; si < 4; si++) {
        int s = s0 + si;
        float spv[K2];
#pragma unroll
        for (int k = 0; k < K2; k++) {
            float a = s_spb[si * K2 + k];
            const float* w = s_spw + (si * K2 + k) * (NC * 9);
#pragma unroll
            for (int c = 0; c < NC; c++)
#pragma unroll
                for (int tt = 0; tt < 9; tt++) a += p[c][tt] * w[c * 9 + tt];
            spv[k] = a;
        }
        int sy = s >> 2, sx = s & 3;
#pragma unroll
        for (int c = 0; c < NC; c++) {
            float a = 0.f;
            const float* chp = s_ch + (si * NC + c) * K2;
#pragma unroll
            for (int k = 0; k < K2; k++) a += p[c][k] * (chp[k] + spv[k]);
            a = fminf(fmaxf(a, 0.f), 255.f);
            out[((size_t)(b * NC + c) * OUT_HW + (y * SCALE + sy)) * OUT_HW + (x * SCALE + sx)] = a;
        }
    }
}

extern "C" void kernel_launch(void* const* d_in, const int* in_sizes, int n_in,
                              void* d_out, int out_size, void* d_ws, size_t ws_size,
                              hipStream_t stream) {
    const float* X = (const float*)d_in[0];
    const float* lstm_w = (const float*)d_in[1];
    const float* lstm_b = (const float*)d_in[2];
    const float* ow[3] = {(const float*)d_in[3], (const float*)d_in[9], (const float*)d_in[15]};
    const float* ob[3] = {(const float*)d_in[4], (const float*)d_in[10], (const float*)d_in[16]};
    const float* mw[3] = {(const float*)d_in[5], (const float*)d_in[11], (const float*)d_in[17]};
    const float* mb[3] = {(const float*)d_in[6], (const float*)d_in[12], (const float*)d_in[18]};
    const float* dw[3] = {(const float*)d_in[7], (const float*)d_in[13], (const float*)d_in[19]};
    const float* db[3] = {(const float*)d_in[8], (const float*)d_in[14], (const float*)d_in[20]};
    const float* conv_w = (const float*)d_in[21];
    const float* conv_b = (const float*)d_in[22];
    const float* sp_w = (const float*)d_in[23];
    const float* sp_b = (const float*)d_in[24];
    const float* ch_w1 = (const float*)d_in[25];
    const float* ch_b1 = (const float*)d_in[26];
    const float* ch_w2 = (const float*)d_in[27];
    const float* ch_b2 = (const float*)d_in[28];

    float* out = (float*)d_out;
    const size_t OUT_IMG = (size_t)B * NC * OUT_HW * OUT_HW;  // 3145728
    const size_t HIDSZ = (size_t)B * NK * HW;                 // 4194304
    float* hid_out = out + OUT_IMG;
    float* cell_out = out + OUT_IMG + HIDSZ;

    float* ws = (float*)d_ws;
    const size_t XCAT = (size_t)B * CIN * HW;  // 4390912
    float* xcatA = ws;            ws += XCAT;
    float* xcatB = ws;            ws += XCAT;
    float* offb = ws;             ws += (size_t)B * 18 * HW;
    float* maskb = ws;            ws += (size_t)B * 9 * HW;
    float* wT[3];
    for (int i = 0; i < 3; i++) { wT[i] = ws; ws += NK * CIN * K2; }
    float* y3 = ws;               ws += (size_t)B * NC * HW;
    float* pooled = ws;           ws += 16;
    float* chbuf = ws;            ws += (size_t)B * S2 * NC * K2;

    dim3 blk(256);
    dim3 blkD(512);
    dim3 g1(B * HW / 256);        // 256 blocks
    dim3 g4(B * HW / 256, 4);
    dim3 g3(B * HW / 256, 3);
    dim3 gd(B * HW / 64);         // 1024 blocks (64-px strips)

    k_lstm<<<g4, blk, 0, stream>>>(X, lstm_w, lstm_b, xcatA, hid_out, cell_out);
    k_copy_lr<<<g1, blk, 0, stream>>>(X, xcatA, xcatB);
    int ntw = NK * CIN * K2;
    for (int i = 0; i < 3; i++)
        k_transw<<<(ntw + 255) / 256, 256, 0, stream>>>(dw[i], wT[i]);

    // layer 1: xcatA -> xcatB
    k_offmask<<<gd, blk, 0, stream>>>(xcatA, ow[0], ob[0], mw[0], mb[0], offb, maskb);
    k_deform<<<gd, blkD, 0, stream>>>(xcatA, offb, maskb, wT[0], db[0], xcatB);
    // layer 2: xcatB -> xcatA
    k_offmask<<<gd, blk, 0, stream>>>(xcatB, ow[1], ob[1], mw[1], mb[1], offb, maskb);
    k_deform<<<gd, blkD, 0, stream>>>(xcatB, offb, maskb, wT[1], db[1], xcatA);
    // layer 3: xcatA -> xcatB
    k_offmask<<<gd, blk, 0, stream>>>(xcatA, ow[2], ob[2], mw[2], mb[2], offb, maskb);
    k_deform<<<gd, blkD, 0, stream>>>(xcatA, offb, maskb, wT[2], db[2], xcatB);

    k_conv3<<<g3, blk, 0, stream>>>(xcatB, conv_w, conv_b, y3);
    k_pool<<<dim3(B * NC), blk, 0, stream>>>(y3, pooled);
    k_ch<<<dim3(1), dim3(64), 0, stream>>>(pooled, ch_w1, ch_b1, ch_w2, ch_b2, chbuf);
    k_ddf<<<g4, blk, 0, stream>>>(y3, sp_w, sp_b, chbuf, out);
}

// Round 7
// 657.277 us; speedup vs baseline: 2.9223x; 1.3682x over previous
//
#include <hip/hip_runtime.h>
#include <hip/hip_bf16.h>
#include <math.h>

// Problem constants
#define NC 3
#define NK 64
#define KK 3
#define K2 9
#define PAD 1
#define SCALE 4
#define S2 16
#define MID 4
#define B 4
#define H 128
#define W 128
#define HW (H*W)          // 16384
#define CIN 67            // NK + NC
#define OUT_HW (H*SCALE)  // 512

typedef short bf16x8 __attribute__((ext_vector_type(8)));
typedef float f32x4 __attribute__((ext_vector_type(4)));

__device__ __forceinline__ float fast_sigmoid(float v) { return 1.f / (1.f + __expf(-v)); }
__device__ __forceinline__ float fast_tanh(float v) { return 2.f / (1.f + __expf(-2.f * v)) - 1.f; }

// fp32 -> bf16 round-to-nearest-even
__device__ __forceinline__ unsigned short f2bf(float f) {
    unsigned int u = __float_as_uint(f);
    unsigned int r = (u + 0x7FFFu + ((u >> 16) & 1u)) >> 16;
    return (unsigned short)r;
}

// load a zero-padded 3x3 patch of one channel plane (HxW) at (y,x)
__device__ __forceinline__ void load_patch(const float* __restrict__ xc, int y, int x, float* p) {
#pragma unroll
    for (int dy = -1; dy <= 1; dy++) {
#pragma unroll
        for (int dx = -1; dx <= 1; dx++) {
            int yy = y + dy, xx = x + dx;
            float v = (yy >= 0 && yy < H && xx >= 0 && xx < W) ? xc[yy * W + xx] : 0.f;
            p[(dy + 1) * 3 + (dx + 1)] = v;
        }
    }
}

// ---------------------------------------------------------------------------
// ConvLSTM with h=0,c=0: only first NC input channels of lstm_w matter;
// f-gate irrelevant (c_prev=0). blockIdx.y selects a 16-channel gate group.
// ---------------------------------------------------------------------------
__global__ __launch_bounds__(256) void k_lstm(const float* __restrict__ X,
                                              const float* __restrict__ lw,
                                              const float* __restrict__ lb,
                                              float* __restrict__ xcatA,
                                              float* __restrict__ hid_out,
                                              float* __restrict__ cell_out) {
    int t = blockIdx.x * blockDim.x + threadIdx.x;
    int b = t >> 14, hw = t & (HW - 1), y = hw >> 7, x = hw & (W - 1);
    int nk0 = blockIdx.y * 16;
    float p[NC][9];
#pragma unroll
    for (int c = 0; c < NC; c++) load_patch(X + (b * NC + c) * HW, y, x, p[c]);
    float* xc = xcatA + (size_t)b * CIN * HW;
    for (int i = 0; i < 16; i++) {
        int nk = nk0 + i;
        float gi = lb[nk], go = lb[2 * NK + nk], gg = lb[3 * NK + nk];
#pragma unroll
        for (int c = 0; c < NC; c++) {
            const float* wi = lw + (size_t)(nk) * (CIN * 9) + c * 9;
            const float* wo = lw + (size_t)(2 * NK + nk) * (CIN * 9) + c * 9;
            const float* wg = lw + (size_t)(3 * NK + nk) * (CIN * 9) + c * 9;
#pragma unroll
            for (int tt = 0; tt < 9; tt++) {
                gi += p[c][tt] * wi[tt];
                go += p[c][tt] * wo[tt];
                gg += p[c][tt] * wg[tt];
            }
        }
        float cv = fast_sigmoid(gi) * fast_tanh(gg);
        float hv = fast_sigmoid(go) * fast_tanh(cv);
        xc[nk * HW + hw] = hv;
        hid_out[(b * NK + nk) * HW + hw] = hv;
        cell_out[(b * NK + nk) * HW + hw] = cv;
    }
}

// copy lr (X) into channels 64..66 of both xcat buffers
__global__ __launch_bounds__(256) void k_copy_lr(const float* __restrict__ X,
                                                 float* __restrict__ xcatA,
                                                 float* __restrict__ xcatB) {
    int t = blockIdx.x * blockDim.x + threadIdx.x;
    int b = t >> 14, hw = t & (HW - 1);
#pragma unroll
    for (int c = 0; c < NC; c++) {
        float v = X[(b * NC + c) * HW + hw];
        xcatA[(size_t)b * CIN * HW + (NK + c) * HW + hw] = v;
        xcatB[(size_t)b * CIN * HW + (NK + c) * HW + hw] = v;
    }
}

// ---------------------------------------------------------------------------
// Prepack deform weights dw[o<64][c<67][k<9] into MFMA A-fragment order, bf16:
// apk[((tap*3+ks)*4+mt)*512 + lane*8 + j] = A[m][kc] where m = mt*16+(lane&15),
// kc = ks*32 + (lane>>4)*8 + j (within-tap channel index; 0 if kc>=67).
// grid 108 blocks x 512 threads.
// ---------------------------------------------------------------------------
__global__ void k_prepA(const float* __restrict__ w, unsigned short* __restrict__ apk) {
    int g = blockIdx.x;            // (tap*3+ks)*4+mt
    int tid = threadIdx.x;         // 0..511
    int lane = tid >> 3, j = tid & 7;
    int mt = g & 3, r = g >> 2;    // r = tap*3+ks
    int ks = r % 3, tap = r / 3;
    int o = mt * 16 + (lane & 15);
    int c = ks * 32 + ((lane >> 4) << 3) + j;
    float val = (c < CIN) ? w[(size_t)o * (CIN * 9) + c * 9 + tap] : 0.f;
    apk[(size_t)g * 512 + tid] = f2bf(val);
}

// ---------------------------------------------------------------------------
// Offset + mask convs, c-split. Block = 256 threads = 64 pixels; the 4 waves
// partition the 67 input channels (16/17/17/17); each wave accumulates all 27
// outputs in VGPRs (static indices only). LDS reduction, then offsets stored
// raw and mask as 2*sigmoid. XCD-contiguous strip swizzle.
// ---------------------------------------------------------------------------
__global__ __launch_bounds__(256, 4) void k_offmask(const float* __restrict__ xcat,
                                                    const float* __restrict__ ow,
                                                    const float* __restrict__ ob,
                                                    const float* __restrict__ mw,
                                                    const float* __restrict__ mb,
                                                    float* __restrict__ offb,
                                                    float* __restrict__ maskb) {
    __shared__ float red[4 * 27 * 64];  // 27648 B
    int lane = threadIdx.x & 63;
    int wid = __builtin_amdgcn_readfirstlane((int)(threadIdx.x >> 6));
    int blk = blockIdx.x;
    int sg = (blk & 7) * 128 + (blk >> 3);  // XCD-contiguous strip id
    int b = sg >> 8;
    int hwbase = (sg & 255) * 64;
    int hw = hwbase + lane, y = hw >> 7, x = hw & (W - 1);
    int c0 = (CIN * wid) >> 2, c1 = (CIN * (wid + 1)) >> 2;

    float acc[27];
#pragma unroll
    for (int i = 0; i < 27; i++) acc[i] = 0.f;
    const float* xb = xcat + (size_t)b * CIN * HW;
    for (int c = c0; c < c1; c++) {
        float p[9];
        load_patch(xb + c * HW, y, x, p);
#pragma unroll
        for (int oc = 0; oc < 18; oc++) {
            const float* w = ow + (size_t)oc * (CIN * 9) + c * 9;
#pragma unroll
            for (int tt = 0; tt < 9; tt++) acc[oc] += p[tt] * w[tt];
        }
#pragma unroll
        for (int oc = 0; oc < 9; oc++) {
            const float* w = mw + (size_t)oc * (CIN * 9) + c * 9;
#pragma unroll
            for (int tt = 0; tt < 9; tt++) acc[18 + oc] += p[tt] * w[tt];
        }
    }
#pragma unroll
    for (int j = 0; j < 27; j++) red[(wid * 27 + j) * 64 + lane] = acc[j];
    __syncthreads();
    for (int idx = threadIdx.x; idx < 27 * 64; idx += 256) {
        int j = idx >> 6, px = idx & 63;
        float s = red[j * 64 + px] + red[(27 + j) * 64 + px]
                + red[(54 + j) * 64 + px] + red[(81 + j) * 64 + px];
        if (j < 18) {
            offb[(b * 18 + j) * HW + hwbase + px] = s + ob[j];
        } else {
            int mj = j - 18;
            maskb[(b * 9 + mj) * HW + hwbase + px] = 2.f * fast_sigmoid(s + mb[mj]);
        }
    }
}

// ---------------------------------------------------------------------------
// Deformable conv as implicit GEMM on MFMA. Block = 256 thr = 64 px strip.
// Per tap: 4 threads/px (csub = wave id) fill bf16 v-tile vbuf[px][96-pad]
// (bilinear gather * mask), barrier; then wave w = M-tile w computes
// 16 o-rows x 64 px with mfma_f32_16x16x32_bf16 over 3 K-steps; barrier.
// K padded 67->96 (A-side zeros + zeroed vbuf pad -> products vanish).
// Layout (HW-verified m89/m120): A[m=lane&15][k=quad*8+j],
// B[k][n=lane&15], D[row=quad*4+reg][col=lane&15].
// VSTRIDE=104: rows 16B-aligned so B-frag = one ds_read_b128.
// ---------------------------------------------------------------------------
#define VSTRIDE 104
__global__ __launch_bounds__(256, 6) void k_deform(const float* __restrict__ xcat,
                                                   const float* __restrict__ offb,
                                                   const float* __restrict__ maskb,
                                                   const unsigned short* __restrict__ apk,
                                                   const float* __restrict__ bias,
                                                   float* __restrict__ xout) {
    __shared__ unsigned short vbuf[64 * VSTRIDE];  // 13312 B
    int tid = threadIdx.x;
    int lane = tid & 63;                            // px within strip
    int wid = __builtin_amdgcn_readfirstlane(tid >> 6);  // csub / M-tile
    int blk = blockIdx.x;
    int sg = (blk & 7) * 128 + (blk >> 3);          // XCD-contiguous strip id
    int b = sg >> 8;
    int hwbase = (sg & 255) * 64;
    int hw = hwbase + lane;
    int y = hw >> 7, x = hw & (W - 1);

    // zero K-pad region c in [67,96) for this px row
    for (int c = 67 + wid; c < 96; c += 4) vbuf[lane * VSTRIDE + c] = 0;

    f32x4 acc[4];
#pragma unroll
    for (int nt = 0; nt < 4; nt++) { f32x4 z = {0.f, 0.f, 0.f, 0.f}; acc[nt] = z; }

    const float* xb = xcat + (size_t)b * CIN * HW;
    int c0 = wid * 17;
    int c1 = (c0 + 17 < CIN) ? c0 + 17 : CIN;

    for (int tap = 0; tap < K2; tap++) {
        // --- fill phase: bilinear setup (redundant x4 per px, cheap) ---
        int ky = tap / 3, kx = tap - ky * 3;
        float offy = offb[(b * 18 + 2 * tap) * HW + hw];
        float offx = offb[(b * 18 + 2 * tap + 1) * HW + hw];
        float m = maskb[(b * 9 + tap) * HW + hw];
        float py = (float)(y + ky - 1) + offy;
        float px_ = (float)(x + kx - 1) + offx;
        float fy = floorf(py), fx = floorf(px_);
        float wy = py - fy, wx = px_ - fx;
        int y0 = (int)fy, x0 = (int)fx;
        int y1 = y0 + 1, x1 = x0 + 1;
        float vy0 = (y0 >= 0 && y0 <= H - 1) ? 1.f : 0.f;
        float vy1 = (y1 >= 0 && y1 <= H - 1) ? 1.f : 0.f;
        float vx0 = (x0 >= 0 && x0 <= W - 1) ? 1.f : 0.f;
        float vx1 = (x1 >= 0 && x1 <= W - 1) ? 1.f : 0.f;
        int yc0 = min(max(y0, 0), H - 1), yc1 = min(max(y1, 0), H - 1);
        int xc0 = min(max(x0, 0), W - 1), xc1 = min(max(x1, 0), W - 1);
        float a00 = (1.f - wy) * (1.f - wx) * m * vy0 * vx0;
        float a01 = (1.f - wy) * wx * m * vy0 * vx1;
        float a10 = wy * (1.f - wx) * m * vy1 * vx0;
        float a11 = wy * wx * m * vy1 * vx1;
        int j00 = yc0 * W + xc0, j01 = yc0 * W + xc1;
        int j10 = yc1 * W + xc0, j11 = yc1 * W + xc1;

        for (int c = c0; c < c1; c++) {
            const float* xc = xb + c * HW;
            float v = a00 * xc[j00] + a01 * xc[j01] + a10 * xc[j10] + a11 * xc[j11];
            vbuf[lane * VSTRIDE + c] = f2bf(v);
        }
        __syncthreads();

        // --- MFMA phase: this wave = M-tile wid ---
#pragma unroll
        for (int ks = 0; ks < 3; ks++) {
            bf16x8 af = *(const bf16x8*)(apk + (size_t)(((tap * 3 + ks) * 4 + wid) * 512 + lane * 8));
#pragma unroll
            for (int nt = 0; nt < 4; nt++) {
                const bf16x8* bp = (const bf16x8*)&vbuf[(nt * 16 + (lane & 15)) * VSTRIDE
                                                        + ks * 32 + ((lane >> 4) << 3)];
                acc[nt] = __builtin_amdgcn_mfma_f32_16x16x32_bf16(af, *bp, acc[nt], 0, 0, 0);
            }
        }
        __syncthreads();
    }

    // --- epilogue: D[row=quad*4+reg][col=lane&15] ---
    int q = lane >> 4, n0 = lane & 15;
    float* xo = xout + (size_t)b * CIN * HW + hwbase;
#pragma unroll
    for (int nt = 0; nt < 4; nt++) {
#pragma unroll
        for (int r = 0; r < 4; r++) {
            int o = wid * 16 + q * 4 + r;
            xo[(size_t)o * HW + nt * 16 + n0] = acc[nt][r] + bias[o];
        }
    }
}

// final 3-channel conv over 67-channel concat; blockIdx.y = output channel
__global__ __launch_bounds__(256) void k_conv3(const float* __restrict__ xcat,
                                               const float* __restrict__ cw,
                                               const float* __restrict__ cb,
                                               float* __restrict__ y3) {
    int t = blockIdx.x * blockDim.x + threadIdx.x;
    int b = t >> 14, hw = t & (HW - 1), y = hw >> 7, x = hw & (W - 1);
    int oc = blockIdx.y;
    float acc = cb[oc];
    const float* xb = xcat + (size_t)b * CIN * HW;
    const float* wb = cw + (size_t)oc * (CIN * 9);
    for (int c = 0; c < CIN; c++) {
        float p[9];
        load_patch(xb + c * HW, y, x, p);
        const float* w = wb + c * 9;
#pragma unroll
        for (int tt = 0; tt < 9; tt++) acc += p[tt] * w[tt];
    }
    y3[(b * NC + oc) * HW + hw] = acc;
}

// global average pool: one block per (b,c)
__global__ __launch_bounds__(256) void k_pool(const float* __restrict__ y3,
                                              float* __restrict__ pooled) {
    int bc = blockIdx.x;  // 0..11
    const float* p = y3 + (size_t)bc * HW;
    float s = 0.f;
    for (int i = threadIdx.x; i < HW; i += 256) s += p[i];
    __shared__ float red[256];
    red[threadIdx.x] = s;
    __syncthreads();
    for (int off = 128; off > 0; off >>= 1) {
        if (threadIdx.x < off) red[threadIdx.x] += red[threadIdx.x + off];
        __syncthreads();
    }
    if (threadIdx.x == 0) pooled[bc] = red[0] / (float)HW;
}

// tiny per-branch channel MLP -> ch[b,s,c,k]
__global__ void k_ch(const float* __restrict__ pooled, const float* __restrict__ w1,
                     const float* __restrict__ b1, const float* __restrict__ w2,
                     const float* __restrict__ b2, float* __restrict__ chbuf) {
    int t = threadIdx.x;
    if (t >= B * S2) return;
    int b = t >> 4, s = t & 15;
    float h1[MID];
#pragma unroll
    for (int m = 0; m < MID; m++) {
        float a = b1[s * MID + m];
#pragma unroll
        for (int c = 0; c < NC; c++) a += pooled[b * NC + c] * w1[(s * MID + m) * NC + c];
        h1[m] = fmaxf(a, 0.f);
    }
    for (int kk = 0; kk < NC * K2; kk++) {
        float a = b2[s * (NC * K2) + kk];
#pragma unroll
        for (int m = 0; m < MID; m++) a += h1[m] * w2[(s * (NC * K2) + kk) * MID + m];
        chbuf[(b * S2 + s) * (NC * K2) + kk] = a;
    }
}

// ---------------------------------------------------------------------------
// Fused DDF upsample: spatial-filter conv + dynamic combine + pixel_shuffle
// + clip. blockIdx.y selects 4 of the 16 branches; that quarter of sp_w/sp_b
// and ch staged in LDS (block is single-batch).
// ---------------------------------------------------------------------------
__global__ __launch_bounds__(256) void k_ddf(const float* __restrict__ y3,
                                             const float* __restrict__ spw,
                                             const float* __restrict__ spb,
                                             const float* __restrict__ chbuf,
                                             float* __restrict__ out) {
    __shared__ float s_spw[4 * K2 * NC * 9];  // 972
    __shared__ float s_spb[4 * K2];           // 36
    __shared__ float s_ch[4 * NC * K2];       // 108
    int t = blockIdx.x * blockDim.x + threadIdx.x;
    int b = t >> 14, hw = t & (HW - 1), y = hw >> 7, x = hw & (W - 1);
    int s0 = blockIdx.y * 4;
    for (int i = threadIdx.x; i < 4 * K2 * NC * 9; i += 256) s_spw[i] = spw[s0 * K2 * NC * 9 + i];
    if (threadIdx.x < 4 * K2) s_spb[threadIdx.x] = spb[s0 * K2 + threadIdx.x];
    if (threadIdx.x < 4 * NC * K2) s_ch[threadIdx.x] = chbuf[b * (S2 * NC * K2) + s0 * NC * K2 + threadIdx.x];
    __syncthreads();
    float p[NC][9];
#pragma unroll
    for (int c = 0; c < NC; c++) load_patch(y3 + (b * NC + c) * HW, y, x, p[c]);
#pragma unroll
    for (int si = 0; si < 4; si++) {
        int s = s0 + si;
        float spv[K2];
#pragma unroll
        for (int k = 0; k < K2; k++) {
            float a = s_spb[si * K2 + k];
            const float* w = s_spw + (si * K2 + k) * (NC * 9);
#pragma unroll
            for (int c = 0; c < NC; c++)
#pragma unroll
                for (int tt = 0; tt < 9; tt++) a += p[c][tt] * w[c * 9 + tt];
            spv[k] = a;
        }
        int sy = s >> 2, sx = s & 3;
#pragma unroll
        for (int c = 0; c < NC; c++) {
            float a = 0.f;
            const float* chp = s_ch + (si * NC + c) * K2;
#pragma unroll
            for (int k = 0; k < K2; k++) a += p[c][k] * (chp[k] + spv[k]);
            a = fminf(fmaxf(a, 0.f), 255.f);
            out[((size_t)(b * NC + c) * OUT_HW + (y * SCALE + sy)) * OUT_HW + (x * SCALE + sx)] = a;
        }
    }
}

extern "C" void kernel_launch(void* const* d_in, const int* in_sizes, int n_in,
                              void* d_out, int out_size, void* d_ws, size_t ws_size,
                              hipStream_t stream) {
    const float* X = (const float*)d_in[0];
    const float* lstm_w = (const float*)d_in[1];
    const float* lstm_b = (const float*)d_in[2];
    const float* ow[3] = {(const float*)d_in[3], (const float*)d_in[9], (const float*)d_in[15]};
    const float* ob[3] = {(const float*)d_in[4], (const float*)d_in[10], (const float*)d_in[16]};
    const float* mw[3] = {(const float*)d_in[5], (const float*)d_in[11], (const float*)d_in[17]};
    const float* mb[3] = {(const float*)d_in[6], (const float*)d_in[12], (const float*)d_in[18]};
    const float* dw[3] = {(const float*)d_in[7], (const float*)d_in[13], (const float*)d_in[19]};
    const float* db[3] = {(const float*)d_in[8], (const float*)d_in[14], (const float*)d_in[20]};
    const float* conv_w = (const float*)d_in[21];
    const float* conv_b = (const float*)d_in[22];
    const float* sp_w = (const float*)d_in[23];
    const float* sp_b = (const float*)d_in[24];
    const float* ch_w1 = (const float*)d_in[25];
    const float* ch_b1 = (const float*)d_in[26];
    const float* ch_w2 = (const float*)d_in[27];
    const float* ch_b2 = (const float*)d_in[28];

    float* out = (float*)d_out;
    const size_t OUT_IMG = (size_t)B * NC * OUT_HW * OUT_HW;  // 3145728
    const size_t HIDSZ = (size_t)B * NK * HW;                 // 4194304
    float* hid_out = out + OUT_IMG;
    float* cell_out = out + OUT_IMG + HIDSZ;

    float* ws = (float*)d_ws;
    const size_t XCAT = (size_t)B * CIN * HW;  // 4390912
    float* xcatA = ws;            ws += XCAT;
    float* xcatB = ws;            ws += XCAT;
    float* offb = ws;             ws += (size_t)B * 18 * HW;
    float* maskb = ws;            ws += (size_t)B * 9 * HW;
    unsigned short* apk[3];
    for (int i = 0; i < 3; i++) { apk[i] = (unsigned short*)ws; ws += 108 * 512 / 2; }  // 55296 bf16 each
    float* y3 = ws;               ws += (size_t)B * NC * HW;
    float* pooled = ws;           ws += 16;
    float* chbuf = ws;            ws += (size_t)B * S2 * NC * K2;

    dim3 blk(256);
    dim3 g1(B * HW / 256);        // 256 blocks
    dim3 g4(B * HW / 256, 4);
    dim3 g3(B * HW / 256, 3);
    dim3 gd(B * HW / 64);         // 1024 blocks (64-px strips)

    k_lstm<<<g4, blk, 0, stream>>>(X, lstm_w, lstm_b, xcatA, hid_out, cell_out);
    k_copy_lr<<<g1, blk, 0, stream>>>(X, xcatA, xcatB);
    for (int i = 0; i < 3; i++)
        k_prepA<<<dim3(108), dim3(512), 0, stream>>>(dw[i], apk[i]);

    // layer 1: xcatA -> xcatB
    k_offmask<<<gd, blk, 0, stream>>>(xcatA, ow[0], ob[0], mw[0], mb[0], offb, maskb);
    k_deform<<<gd, blk, 0, stream>>>(xcatA, offb, maskb, apk[0], db[0], xcatB);
    // layer 2: xcatB -> xcatA
    k_offmask<<<gd, blk, 0, stream>>>(xcatB, ow[1], ob[1], mw[1], mb[1], offb, maskb);
    k_deform<<<gd, blk, 0, stream>>>(xcatB, offb, maskb, apk[1], db[1], xcatA);
    // layer 3: xcatA -> xcatB
    k_offmask<<<gd, blk, 0, stream>>>(xcatA, ow[2], ob[2], mw[2], mb[2], offb, maskb);
    k_deform<<<gd, blk, 0, stream>>>(xcatA, offb, maskb, apk[2], db[2], xcatB);

    k_conv3<<<g3, blk, 0, stream>>>(xcatB, conv_w, conv_b, y3);
    k_pool<<<dim3(B * NC), blk, 0, stream>>>(y3, pooled);
    k_ch<<<dim3(1), dim3(64), 0, stream>>>(pooled, ch_w1, ch_b1, ch_w2, ch_b2, chbuf);
    k_ddf<<<g4, blk, 0, stream>>>(y3, sp_w, sp_b, chbuf, out);
}